// Round 7
// baseline (325.231 us; speedup 1.0000x reference)
//
#include <hip/hip_runtime.h>
#include <math.h>

#define NB 16
#define NC 48
#define NT 96
#define NP 12
#define NFF 64
#define CT 4608          // NC*NT
#define STEPS 7
#define NBLK 768         // 768 blocks * 3 waves = 2304 edge waves; EXACTLY 3/CU
#define NTHR 192

// ---- fence-free grid barrier (r6-proven): 24-lane tree + 24-word bcast ----
// All cross-block data via relaxed agent-scope atomics (LLC-direct). Ordering:
// __syncthreads drains each wave's vmcnt (stores complete at LLC before tid0
// arrives); arrive->root->bcast chain is value-dependent; no fences needed.
#define NLANE 24
#define LSTRIDE 32   // words => 128 B between counters/words

__device__ unsigned g_sub[NLANE * LSTRIDE];   // zero-init at module load
__device__ unsigned g_root = 0;
__device__ unsigned g_bcast[NLANE * LSTRIDE];

__device__ __forceinline__ void stg_llc(float* p, float v) {
    __hip_atomic_store(p, v, __ATOMIC_RELAXED, __HIP_MEMORY_SCOPE_AGENT);
}
__device__ __forceinline__ float ldg_llc(const float* p) {
    return __hip_atomic_load(p, __ATOMIC_RELAXED, __HIP_MEMORY_SCOPE_AGENT);
}

// single tree, 768 arrivals = 24 lanes x 32; reuse gap = a full step (us) >>
// reset completion (ns). Entry gen0 snapshot quiescent: first bump needs all
// 768 arrivals, so every block's entry read precedes any bcast write.
__device__ __forceinline__ void tree_arrive(int lane, unsigned target) {
    unsigned old = __hip_atomic_fetch_add(&g_sub[lane * LSTRIDE], 1u,
                                          __ATOMIC_RELAXED, __HIP_MEMORY_SCOPE_AGENT);
    if (old == 32u - 1u) {
        __hip_atomic_store(&g_sub[lane * LSTRIDE], 0u, __ATOMIC_RELAXED,
                           __HIP_MEMORY_SCOPE_AGENT);
        unsigned r = __hip_atomic_fetch_add(&g_root, 1u, __ATOMIC_RELAXED,
                                            __HIP_MEMORY_SCOPE_AGENT);
        if (r == NLANE - 1u) {
            __hip_atomic_store(&g_root, 0u, __ATOMIC_RELAXED, __HIP_MEMORY_SCOPE_AGENT);
#pragma unroll
            for (int g = 0; g < NLANE; g++)
                __hip_atomic_store(&g_bcast[g * LSTRIDE], target, __ATOMIC_RELAXED,
                                   __HIP_MEMORY_SCOPE_AGENT);
        }
    }
}
__device__ __forceinline__ void bar_wait(int grp, unsigned target) {
    while ((int)(__hip_atomic_load(&g_bcast[grp * LSTRIDE], __ATOMIC_RELAXED,
                                   __HIP_MEMORY_SCOPE_AGENT) - target) < 0)
        __builtin_amdgcn_s_sleep(1);
    asm volatile("" ::: "memory");   // no load hoisting above the poll
}

// ---- exact-GELU via Abramowitz-Stegun 7.1.26 erf (|abs err| <= 1.5e-7) ----
__device__ __forceinline__ float erf_fast(float x) {
    float a = fabsf(x);
    float t = __builtin_amdgcn_rcpf(fmaf(0.3275911f, a, 1.0f));
    float p = t * fmaf(t, fmaf(t, fmaf(t, fmaf(t, 1.061405429f, -1.453152027f),
                                       1.421413741f), -0.284496736f), 0.254829592f);
    float E = __builtin_amdgcn_exp2f(-a * a * 1.4426950408889634f);
    float y = fmaf(-p, E, 1.0f);
    return copysignf(y, x);
}
__device__ __forceinline__ float gelu_exact(float u) {
    float e  = erf_fast(u * 0.70710678118654752f);
    float hu = 0.5f * u;
    return fmaf(hu, e, hu);
}

// insert candidate (ev,ej) into sorted top-3; value desc, index asc on ties
#define INSERT3(ev, ej)                                                   \
    {                                                                     \
        bool w0_ = (ev > v0) || (ev == v0 && ej < j0);                    \
        bool w1_ = (ev > v1) || (ev == v1 && ej < j1);                    \
        bool w2_ = (ev > v2) || (ev == v2 && ej < j2);                    \
        if (w0_)      { v2 = v1; j2 = j1; v1 = v0; j1 = j0; v0 = ev; j0 = ej; } \
        else if (w1_) { v2 = v1; j2 = j1; v1 = ev; j1 = ej; }             \
        else if (w2_) { v2 = ev; j2 = ej; }                               \
    }

#define CSWAP(va, ja, vb, jb)                                             \
    {                                                                     \
        bool sw_ = (vb > va) || (vb == va && jb < ja);                    \
        float ov_ = va; int oj_ = ja;                                     \
        va = sw_ ? vb : va; ja = sw_ ? jb : ja;                           \
        vb = sw_ ? ov_ : vb; jb = sw_ ? oj_ : jb;                        \
    }

// Merged-uniform design: every block replicates the (tiny) phase1 slice it
// needs, entirely in LDS; only cross-block array is the `out` step panel.
// Barriers: A(s), s=0..5, target gen0+s+1 (6 per launch, single tree).
// LDS 44.4 KB/block forces exactly 3 blocks/CU -> 768 = 3*256 all resident,
// perfectly uniform (no straggler CUs), deadlock-safe by construction.
__global__ __launch_bounds__(NTHR, 3) void fused_kernel(
    const float* __restrict__ x,
    const float* __restrict__ g0, const float* __restrict__ b0,
    const float* __restrict__ g1, const float* __restrict__ b1,
    const float* __restrict__ g2, const float* __restrict__ b2,
    const float* __restrict__ Wagg, const float* __restrict__ bagg,
    const float* __restrict__ W1, const float* __restrict__ bm1,
    const float* __restrict__ W2, const float* __restrict__ wmsg,
    const float* __restrict__ bmsg,
    float* __restrict__ out)
{
    const int tid = threadIdx.x;
    const int bk  = blockIdx.x;
    const int lane24 = bk % NLANE;

    __shared__ float  inpL[NB * 624];   // [b][c*13+pp], pad 13 -> conflict-free
    __shared__ float  resL[NC * 17];    // [c][b], pad 17
    __shared__ float  tL[NC];
    __shared__ float4 coef[NFF];

    unsigned gen0 = 0;
    if (tid == 0)
        gen0 = __hip_atomic_load(&g_bcast[lane24 * LSTRIDE], __ATOMIC_RELAXED,
                                 __HIP_MEMORY_SCOPE_AGENT);

    // block identity: one (b̂,p̂) per block; 4 consecutive blocks share a bp
    const int bp = bk >> 2;            // 0..191
    const int bB = bp / NP;            // b̂
    const int pP = bp - bB * NP;       // p̂

    // edge identity: wave wid handles rows iq*4..iq*4+3
    const int wid  = tid >> 6;
    const int lane = tid & 63;
    const int rl   = lane >> 4;
    const int jg   = lane & 15;
    const int iq   = (bk & 3) * 3 + wid;   // 0..11
    const int e_i  = iq * 4 + rl;          // 0..47

    if (tid < NFF) coef[tid] = make_float4(W1[2 * tid], W1[2 * tid + 1], bm1[tid], W2[tid]);
    const float wmsg0 = wmsg[0], bmsg0 = bmsg[0];

    // Wagg row p̂ (block-uniform)
    float waggR[NP];
#pragma unroll
    for (int pp = 0; pp < NP; pp++) waggR[pp] = Wagg[pP * NP + pp];
    const float baggv = bagg[pP];

    // matmul identity: thread owns c = tid%48, b = tid/48 + 4k
    const int mc  = tid % NC;
    const int mb0 = tid / NC;

    for (int s = 0; s < STEPS; s++) {
        if (s > 0) {
            if (tid == 0) bar_wait(lane24, gen0 + s);   // A(s-1): prev panel ready
            __syncthreads();
        }

        // ---- BN1 (+local BN0 at s==0) for 3 features/thread -> inpL ----
#pragma unroll
        for (int k = 0; k < 3; k++) {
            const int f = tid + 192 * k;       // 576 = 192*3 exact
            const int c = f / NP, pp = f - c * NP;
            float v[NB];
            if (s == 0) {
                float sum = 0.f;
#pragma unroll
                for (int b = 0; b < NB; b++) { v[b] = x[b * CT + c * NT + pp]; sum += v[b]; }
                float mu = sum * (1.f / NB), var = 0.f;
#pragma unroll
                for (int b = 0; b < NB; b++) { float d = v[b] - mu; var = fmaf(d, d, var); }
                var *= (1.f / NB);
                float rs = rsqrtf(var + 1e-5f);
                float gg = g0[c * NT + pp], bb = b0[c * NT + pp];
#pragma unroll
                for (int b = 0; b < NB; b++) v[b] = (v[b] - mu) * rs * gg + bb;
                if (bk == c) {              // blocks 0..47 write the 'first' slice
#pragma unroll
                    for (int b = 0; b < NB; b++) out[(b * NC + c) * NT + pp] = v[b];
                }
            } else {
#pragma unroll
                for (int b = 0; b < NB; b++)
                    v[b] = ldg_llc(&out[(b * NC + c) * NT + NP * s + pp]);
            }
            float sum = 0.f;
#pragma unroll
            for (int b = 0; b < NB; b++) sum += v[b];
            float mu = sum * (1.f / NB), var = 0.f;
#pragma unroll
            for (int b = 0; b < NB; b++) { float d = v[b] - mu; var = fmaf(d, d, var); }
            var *= (1.f / NB);
            float rs = rsqrtf(var + 1e-5f);
            float gg = g1[c * NP + pp], bb = b1[c * NP + pp];
#pragma unroll
            for (int b = 0; b < NB; b++)
                inpL[b * 624 + c * 13 + pp] = (v[b] - mu) * rs * gg + bb;
        }
        __syncthreads();

        // ---- agg matmul (row p̂) + gelu + xn -> resL[c][b] (4 outputs/thread) ----
        {
            const int tt2 = NP * (s + 1) + pP;   // <= 95
            float xv[NB]; float sum = 0.f;
#pragma unroll
            for (int b = 0; b < NB; b++) { xv[b] = x[b * CT + mc * NT + tt2]; sum += xv[b]; }
            float mu = sum * (1.f / NB), var = 0.f;
#pragma unroll
            for (int b = 0; b < NB; b++) { float d = xv[b] - mu; var = fmaf(d, d, var); }
            var *= (1.f / NB);
            float rs = rsqrtf(var + 1e-5f);
            float gg = g0[mc * NT + tt2], bb = b0[mc * NT + tt2];
#pragma unroll
            for (int k = 0; k < 4; k++) {
                const int b = mb0 + 4 * k;           // runtime b: re-load from global
                float xb = x[b * CT + mc * NT + tt2];  // (L2-hot; avoids reg-array idx)
                float acc = baggv;
#pragma unroll
                for (int pp = 0; pp < NP; pp++)
                    acc = fmaf(inpL[b * 624 + mc * 13 + pp], waggR[pp], acc);
                resL[mc * 17 + b] = gelu_exact(acc) + (xb - mu) * rs * gg + bb;
            }
        }
        __syncthreads();

        // ---- BN2 over b -> tL[c] (b̂'s normalized value only) ----
        if (tid < NC) {
            float sum = 0.f;
#pragma unroll
            for (int b = 0; b < NB; b++) sum += resL[tid * 17 + b];
            float mu = sum * (1.f / NB), var = 0.f;
#pragma unroll
            for (int b = 0; b < NB; b++) { float d = resL[tid * 17 + b] - mu; var = fmaf(d, d, var); }
            var *= (1.f / NB);
            tL[tid] = (resL[tid * 17 + bB] - mu) * rsqrtf(var + 1e-5f)
                          * g2[tid * NP + pP] + b2[tid * NP + pP];
        }
        __syncthreads();

        // ---- edge MLP + top-3 + softmax + message (unchanged math, t/res in LDS) ----
        {
            float zi  = tL[e_i];
            float zj0 = tL[jg], zj1 = tL[jg + 16], zj2 = tL[jg + 32];
            float e0 = 0.f, e1 = 0.f, e2 = 0.f;
#pragma unroll 8
            for (int ff = 0; ff < NFF; ff++) {
                float4 cf = coef[ff];
                float base = fmaf(cf.x, zi, cf.z);
                e0 = fmaf(gelu_exact(fmaf(cf.y, zj0, base)), cf.w, e0);
                e1 = fmaf(gelu_exact(fmaf(cf.y, zj1, base)), cf.w, e1);
                e2 = fmaf(gelu_exact(fmaf(cf.y, zj2, base)), cf.w, e2);
            }
            float v0 = e0, v1 = e1, v2 = e2;
            int   j0 = jg, j1 = jg + 16, j2 = jg + 32;
            CSWAP(v0, j0, v1, j1);
            CSWAP(v1, j1, v2, j2);
            CSWAP(v0, j0, v1, j1);
#pragma unroll
            for (int off = 1; off < 16; off <<= 1) {
                float o0 = __shfl_xor(v0, off), o1 = __shfl_xor(v1, off), o2 = __shfl_xor(v2, off);
                int   q0 = __shfl_xor(j0, off), q1 = __shfl_xor(j1, off), q2 = __shfl_xor(j2, off);
                INSERT3(o0, q0);
                INSERT3(o1, q1);
                INSERT3(o2, q2);
            }
            const float L2E = 1.4426950408889634f;
            float ww1 = __builtin_amdgcn_exp2f((v1 - v0) * L2E);
            float ww2 = __builtin_amdgcn_exp2f((v2 - v0) * L2E);
            float wsum = 1.f + ww1 + ww2;
            float tsum = fmaf(ww2, tL[j2], fmaf(ww1, tL[j1], tL[j0]));
            float znew = fmaf(wmsg0, tsum / wsum, bmsg0);
            if (jg == 0) {
                float res = resL[e_i * 17 + bB];
                stg_llc(&out[(bB * NC + e_i) * NT + NP * (s + 1) + pP],
                        fmaf(0.5f, znew, res));              // ALPHA = 0.5
            }
        }
        __syncthreads();   // all waves' out-stores drained (vmcnt) before arrive
        if (s < STEPS - 1 && tid == 0) tree_arrive(lane24, gen0 + s + 1);  // A(s)
    }
}

extern "C" void kernel_launch(void* const* d_in, const int* in_sizes, int n_in,
                              void* d_out, int out_size, void* d_ws, size_t ws_size,
                              hipStream_t stream)
{
    const float* x    = (const float*)d_in[0];
    const float* g0   = (const float*)d_in[1];
    const float* b0   = (const float*)d_in[2];
    const float* g1   = (const float*)d_in[3];
    const float* b1   = (const float*)d_in[4];
    const float* g2   = (const float*)d_in[5];
    const float* b2   = (const float*)d_in[6];
    const float* Wagg = (const float*)d_in[7];
    const float* bagg = (const float*)d_in[8];
    const float* W1   = (const float*)d_in[9];
    const float* bm1  = (const float*)d_in[10];
    const float* W2   = (const float*)d_in[11];
    // d_in[12] = bm2: uniform shift of e -> invariant under top-k & softmax; unused
    const float* wmsg = (const float*)d_in[13];
    const float* bmsg = (const float*)d_in[14];
    float* out = (float*)d_out;

    fused_kernel<<<dim3(NBLK), dim3(NTHR), 0, stream>>>(
        x, g0, b0, g1, b1, g2, b2, Wagg, bagg, W1, bm1, W2, wmsg, bmsg, out);
}

// Round 8
// 306.173 us; speedup vs baseline: 1.0622x; 1.0622x over previous
//
#include <hip/hip_runtime.h>
#include <math.h>

#define NB 16
#define NC 48
#define NT 96
#define NP 12
#define NFF 64
#define CT 4608          // NC*NT
#define STEPS 7
#define NEDGE 256        // edge blocks: 256 x 4 waves = 1024 waves = 1/SIMD exact
#define NP1 48           // dedicated phase1 blocks (one per channel c)
#define NBLK (NEDGE + NP1)   // 304 blocks; 48 CUs get 2, rest 1 -> all resident
#define NTHR 256

// ---- fence-free grid barrier (r6-proven): 16-lane tree + 16-word bcast ----
// All cross-block data via relaxed agent-scope atomics (LLC-direct). Ordering:
// __syncthreads drains each wave's vmcnt (stores complete at LLC before tid0
// arrives); arrive->root->bcast chain is value-dependent; no fences needed.
#define NLANE 16
#define LSTRIDE 32   // words => 128 B between counters/words

__device__ unsigned g_subA[NLANE * LSTRIDE];   // zero-init at module load
__device__ unsigned g_subB[NLANE * LSTRIDE];
__device__ unsigned g_rootA = 0;
__device__ unsigned g_rootB = 0;
__device__ unsigned g_bcast[NLANE * LSTRIDE];

__device__ __forceinline__ void stg_llc(float* p, float v) {
    __hip_atomic_store(p, v, __ATOMIC_RELAXED, __HIP_MEMORY_SCOPE_AGENT);
}
__device__ __forceinline__ float ldg_llc(const float* p) {
    return __hip_atomic_load(p, __ATOMIC_RELAXED, __HIP_MEMORY_SCOPE_AGENT);
}

__device__ __forceinline__ void tree_arrive(unsigned* subs, unsigned* root,
                                            int lane, unsigned laneTh,
                                            unsigned target) {
    unsigned old = __hip_atomic_fetch_add(&subs[lane * LSTRIDE], 1u,
                                          __ATOMIC_RELAXED, __HIP_MEMORY_SCOPE_AGENT);
    if (old == laneTh - 1u) {
        __hip_atomic_store(&subs[lane * LSTRIDE], 0u, __ATOMIC_RELAXED,
                           __HIP_MEMORY_SCOPE_AGENT);
        unsigned r = __hip_atomic_fetch_add(root, 1u, __ATOMIC_RELAXED,
                                            __HIP_MEMORY_SCOPE_AGENT);
        if (r == NLANE - 1u) {
            __hip_atomic_store(root, 0u, __ATOMIC_RELAXED, __HIP_MEMORY_SCOPE_AGENT);
#pragma unroll
            for (int g = 0; g < NLANE; g++)
                __hip_atomic_store(&g_bcast[g * LSTRIDE], target, __ATOMIC_RELAXED,
                                   __HIP_MEMORY_SCOPE_AGENT);
        }
    }
}
__device__ __forceinline__ void bar_wait(int grp, unsigned target) {
    while ((int)(__hip_atomic_load(&g_bcast[grp * LSTRIDE], __ATOMIC_RELAXED,
                                   __HIP_MEMORY_SCOPE_AGENT) - target) < 0)
        __builtin_amdgcn_s_sleep(1);
    asm volatile("" ::: "memory");   // no load hoisting above the poll
}

// ---- exact-GELU via Abramowitz-Stegun 7.1.26 erf (|abs err| <= 1.5e-7) ----
__device__ __forceinline__ float erf_fast(float x) {
    float a = fabsf(x);
    float t = __builtin_amdgcn_rcpf(fmaf(0.3275911f, a, 1.0f));
    float p = t * fmaf(t, fmaf(t, fmaf(t, fmaf(t, 1.061405429f, -1.453152027f),
                                       1.421413741f), -0.284496736f), 0.254829592f);
    float E = __builtin_amdgcn_exp2f(-a * a * 1.4426950408889634f);
    float y = fmaf(-p, E, 1.0f);
    return copysignf(y, x);
}
__device__ __forceinline__ float gelu_exact(float u) {
    float e  = erf_fast(u * 0.70710678118654752f);
    float hu = 0.5f * u;
    return fmaf(hu, e, hu);
}

// insert candidate (ev,ej) into sorted top-3; value desc, index asc on ties
#define INSERT3(ev, ej)                                                   \
    {                                                                     \
        bool w0_ = (ev > v0) || (ev == v0 && ej < j0);                    \
        bool w1_ = (ev > v1) || (ev == v1 && ej < j1);                    \
        bool w2_ = (ev > v2) || (ev == v2 && ej < j2);                    \
        if (w0_)      { v2 = v1; j2 = j1; v1 = v0; j1 = j0; v0 = ev; j0 = ej; } \
        else if (w1_) { v2 = v1; j2 = j1; v1 = ev; j1 = ej; }             \
        else if (w2_) { v2 = ev; j2 = ej; }                               \
    }

#define CSWAP(va, ja, vb, jb)                                             \
    {                                                                     \
        bool sw_ = (vb > va) || (vb == va && jb < ja);                    \
        float ov_ = va; int oj_ = ja;                                     \
        va = sw_ ? vb : va; ja = sw_ ? jb : ja;                           \
        vb = sw_ ? ov_ : vb; jb = sw_ ? oj_ : jb;                        \
    }

// Barrier map (targets relative to gen0 snapshot), 13 per launch:
//   B(0): tree B, laneTh 19 (all 304 blocks), target 1   (entry handshake)
//   B(s): tree B, laneTh 3  (48 phase1 blocks), target 2s+1, s>=1
//   A(s): tree A, laneTh 16 (256 edge blocks),  target 2s+2
__global__ __launch_bounds__(NTHR, 2) void fused_kernel(
    const float* __restrict__ x,
    const float* __restrict__ g0, const float* __restrict__ b0,
    const float* __restrict__ g1, const float* __restrict__ b1,
    const float* __restrict__ g2, const float* __restrict__ b2,
    const float* __restrict__ Wagg, const float* __restrict__ bagg,
    const float* __restrict__ W1, const float* __restrict__ bm1,
    const float* __restrict__ W2, const float* __restrict__ wmsg,
    const float* __restrict__ bmsg,
    float* __restrict__ t_ws, float* __restrict__ res_ws,
    float* __restrict__ out)
{
    const int tid = threadIdx.x;
    const int bk  = blockIdx.x;
    const int lane16 = bk & (NLANE - 1);

    __shared__ float  xnL[NB][NT + 1];   // phase1 blocks only
    __shared__ float  shB[NB * NP];
    __shared__ float  wagg[NP * NP];
    __shared__ float  eL[4 * 9 * 49];    // edge blocks: per-wave [9 rows][49]
    __shared__ float4 coef[NFF];

    unsigned gen0 = 0;
    if (tid == 0)
        gen0 = __hip_atomic_load(&g_bcast[lane16 * LSTRIDE], __ATOMIC_RELAXED,
                                 __HIP_MEMORY_SCOPE_AGENT);

    if (bk >= NEDGE) {
        // ==================== dedicated phase1 block: c = bk - NEDGE (r6 verbatim) ====================
        const int c = bk - NEDGE;
        const int p = tid >> 4;          // p in [0,12) for tid<192
        const int b = tid & 15;          // b in [0,16)
        float g1v = 0.f, b1v = 0.f, g2v = 0.f, b2v = 0.f, baggv = 0.f;
        if (tid < NP * NP) wagg[tid] = Wagg[tid];
        if (tid < 192) {
            g1v = g1[c * NP + p]; b1v = b1[c * NP + p];
            g2v = g2[c * NP + p]; b2v = b2[c * NP + p];
            baggv = bagg[p];
        }
        if (tid < NT) {
            const int tt = tid;
            float v[NB]; float sum = 0.f;
#pragma unroll
            for (int bb = 0; bb < NB; bb++) { v[bb] = x[bb * CT + c * NT + tt]; sum += v[bb]; }
            float mu = sum * (1.f / NB);
            float var = 0.f;
#pragma unroll
            for (int bb = 0; bb < NB; bb++) { float d = v[bb] - mu; var = fmaf(d, d, var); }
            var *= (1.f / NB);
            float rs = rsqrtf(var + 1e-5f);
            float gg = g0[c * NT + tt], bbv = b0[c * NT + tt];
#pragma unroll
            for (int bb = 0; bb < NB; bb++) {
                float y = (v[bb] - mu) * rs * gg + bbv;
                xnL[bb][tt] = y;
                if (tt < NP) out[(bb * NC + c) * NT + tt] = y;
            }
        }
        __syncthreads();

        for (int s = 0; s < STEPS; s++) {
            if (s > 0) {
                if (tid == 0) bar_wait(lane16, gen0 + 2 * s);   // A(s-1)
                __syncthreads();
            }
            if (tid < 192) {
                float v = (s == 0) ? xnL[b][p]
                                   : ldg_llc(&out[(b * NC + c) * NT + NP * s + p]);
                float s1 = v;
#pragma unroll
                for (int off = 1; off < 16; off <<= 1) s1 += __shfl_xor(s1, off);
                float mu = s1 * (1.f / NB);
                float d  = v - mu;
                float q  = d * d;
#pragma unroll
                for (int off = 1; off < 16; off <<= 1) q += __shfl_xor(q, off);
                float var = q * (1.f / NB);
                float inp = d * rsqrtf(var + 1e-5f) * g1v + b1v;
                shB[b * NP + p] = inp;
            }
            __syncthreads();
            if (tid < 192) {
                float acc = baggv;
#pragma unroll
                for (int pp = 0; pp < NP; pp++)
                    acc = fmaf(shB[b * NP + pp], wagg[p * NP + pp], acc);
                float res = gelu_exact(acc) + xnL[b][NP + NP * s + p];
                stg_llc(&res_ws[(b * NC + c) * NP + p], res);
                float s2 = res;
#pragma unroll
                for (int off = 1; off < 16; off <<= 1) s2 += __shfl_xor(s2, off);
                float mu2 = s2 * (1.f / NB);
                float d2  = res - mu2;
                float q2  = d2 * d2;
#pragma unroll
                for (int off = 1; off < 16; off <<= 1) q2 += __shfl_xor(q2, off);
                float var2 = q2 * (1.f / NB);
                float t = d2 * rsqrtf(var2 + 1e-5f) * g2v + b2v;
                stg_llc(&t_ws[(b * NP + p) * NC + c], t);    // t[b][p][c]
            }
            __syncthreads();   // drains all waves' vmcnt -> stores at LLC
            if (tid == 0)
                tree_arrive(g_subB, &g_rootB, lane16,
                            s == 0 ? 19u : 3u, gen0 + 2 * s + 1);   // B(s)
        }
        return;
    }

    // ==================== edge block: 4 waves, 9 rows per wave ====================
    if (tid < NFF) coef[tid] = make_float4(W1[2 * tid], W1[2 * tid + 1], bm1[tid], W2[tid]);
    const float wmsg0 = wmsg[0], bmsg0 = bmsg[0];

    const int wid  = tid >> 6;
    const int lane = tid & 63;
    const int grp  = lane >> 4;          // 16-lane group 0..3
    const int jg   = lane & 15;
    const int wgid = bk * 4 + wid;       // 0..1023; rows 9*wgid .. 9*wgid+8

    // initial per-lane (i,j) pair state: pair g = lane; i = g/48, j = g%48
    const int il0 = lane / 48;           // local row 0 or 1
    const int j0i = lane - il0 * 48;
    const int row0 = 9 * wgid + il0;
    const int bp0  = row0 / 48;
    const int b48_0 = bp0 * 48;
    const int iG0   = row0 - b48_0;
    float* eW = &eL[wid * 441];          // this wave's 9x49 tile

    __syncthreads();
    if (tid == 0)
        tree_arrive(g_subB, &g_rootB, lane16, 19u, gen0 + 1);  // entry into B(0)

    for (int s = 0; s < STEPS; s++) {
        if (tid == 0) bar_wait(lane16, gen0 + 2 * s + 1);  // B(s): t_ws ready
        __syncthreads();

        // ---- pair loop: 7 rounds x 64 lanes = 448 slots, 432 active ----
        int il = il0, jj = j0i, b48 = b48_0, ig = iG0;
        float zi = ldg_llc(&t_ws[b48 + ig]);
        float zj = ldg_llc(&t_ws[b48 + jj]);
#pragma unroll
        for (int t = 0; t < 7; t++) {
            const int il_c = il, jj_c = jj;
            const float zi_c = zi, zj_c = zj;
            // advance to next round's pair (g += 64) + prefetch
            bool ge2 = (jj >= 32);
            ig += ge2 ? 2 : 1;
            il += ge2 ? 2 : 1;
            jj  = ge2 ? jj - 32 : jj + 16;
            if (ig >= 48) { ig -= 48; b48 += 48; }
            zi = ldg_llc(&t_ws[b48 + ig]);
            zj = ldg_llc(&t_ws[b48 + jj]);
            // compute e(i,j) with current pair
            float e = 0.f;
#pragma unroll 8
            for (int ff = 0; ff < NFF; ff++) {
                float4 cf = coef[ff];
                float u = fmaf(cf.y, zj_c, fmaf(cf.x, zi_c, cf.z));
                e = fmaf(gelu_exact(u), cf.w, e);
            }
            if (il_c < 9) eW[il_c * 49 + jj_c] = e;
        }
        // wave-local LDS dependency only (same wave wrote eW) -> no barrier

        // ---- top-3 + softmax + message: 3 sub-rounds x 4 groups over 9 rows ----
#pragma unroll
        for (int sr = 0; sr < 3; sr++) {
            const int slot = sr * 4 + grp;
            if (slot < 9) {
                const int row  = 9 * wgid + slot;
                float e0 = eW[slot * 49 + jg];
                float e1 = eW[slot * 49 + jg + 16];
                float e2 = eW[slot * 49 + jg + 32];
                // local sort-3 (value desc, index asc)  [r6 verbatim]
                float v0 = e0, v1 = e1, v2 = e2;
                int   j0 = jg, j1 = jg + 16, j2 = jg + 32;
                CSWAP(v0, j0, v1, j1);
                CSWAP(v1, j1, v2, j2);
                CSWAP(v0, j0, v1, j1);
#pragma unroll
                for (int off = 1; off < 16; off <<= 1) {
                    float o0 = __shfl_xor(v0, off), o1 = __shfl_xor(v1, off), o2 = __shfl_xor(v2, off);
                    int   q0 = __shfl_xor(j0, off), q1 = __shfl_xor(j1, off), q2 = __shfl_xor(j2, off);
                    INSERT3(o0, q0);
                    INSERT3(o1, q1);
                    INSERT3(o2, q2);
                }
                const float L2E = 1.4426950408889634f;
                float ww1 = __builtin_amdgcn_exp2f((v1 - v0) * L2E);
                float ww2 = __builtin_amdgcn_exp2f((v2 - v0) * L2E);
                float wsum = 1.f + ww1 + ww2;
                const int bpr  = row / 48;
                const int b48r = bpr * 48;
                float tsum = fmaf(ww2, ldg_llc(&t_ws[b48r + j2]),
                                  fmaf(ww1, ldg_llc(&t_ws[b48r + j1]),
                                       ldg_llc(&t_ws[b48r + j0])));
                float znew = fmaf(wmsg0, tsum / wsum, bmsg0);
                if (jg == 0) {
                    const int ii = row - b48r;
                    const int bb = bpr / NP;
                    const int pp = bpr - bb * NP;
                    float res = ldg_llc(&res_ws[(bb * NC + ii) * NP + pp]);
                    stg_llc(&out[(bb * NC + ii) * NT + NP * (s + 1) + pp],
                            fmaf(0.5f, znew, res));          // ALPHA = 0.5
                }
            }
        }

        if (s < STEPS - 1) {
            __syncthreads();   // all waves' out-stores drained before arrive
            if (tid == 0)
                tree_arrive(g_subA, &g_rootA, lane16, 16u, gen0 + 2 * s + 2); // A(s)
        }
    }
}

extern "C" void kernel_launch(void* const* d_in, const int* in_sizes, int n_in,
                              void* d_out, int out_size, void* d_ws, size_t ws_size,
                              hipStream_t stream)
{
    const float* x    = (const float*)d_in[0];
    const float* g0   = (const float*)d_in[1];
    const float* b0   = (const float*)d_in[2];
    const float* g1   = (const float*)d_in[3];
    const float* b1   = (const float*)d_in[4];
    const float* g2   = (const float*)d_in[5];
    const float* b2   = (const float*)d_in[6];
    const float* Wagg = (const float*)d_in[7];
    const float* bagg = (const float*)d_in[8];
    const float* W1   = (const float*)d_in[9];
    const float* bm1  = (const float*)d_in[10];
    const float* W2   = (const float*)d_in[11];
    // d_in[12] = bm2: uniform shift of e -> invariant under top-k & softmax; unused
    const float* wmsg = (const float*)d_in[13];
    const float* bmsg = (const float*)d_in[14];
    float* out = (float*)d_out;

    float* t_ws   = (float*)d_ws;            // 9216 floats
    float* res_ws = t_ws + (NB * NP * NC);   // 9216 floats

    fused_kernel<<<dim3(NBLK), dim3(NTHR), 0, stream>>>(
        x, g0, b0, g1, b1, g2, b2, Wagg, bagg, W1, bm1, W2, wmsg, bmsg,
        t_ws, res_ws, out);
}